// Round 1
// baseline (322.682 us; speedup 1.0000x reference)
//
#include <hip/hip_runtime.h>
#include <hip/hip_bf16.h>
#include <stdint.h>

#define H_HT 26
#define W_HT 122
#define NPIX (H_HT * W_HT)   // 3172
#define NA 60
#define NR 125
#define NROW (NPIX * NA)     // 190320
#define TOTE (NROW * NR)     // 23790000
#define NB 32
#define NC 4
#define PH 288
#define PW 800

// ---------------- Kernel A: extract one-hot rho index from vote_index -------
// vote_index layout: [h][w][a][r], exactly one 1.0f per (h,w,a) row of 125.
// Output ri layout: [a][h*122+w] as uint8 (angle-major for coalesced reads in B).
__global__ __launch_bounds__(256) void build_ri(const float* __restrict__ vote,
                                                uint8_t* __restrict__ ri) {
    const int FPB = 16000;                 // floats per block (64 KB)
    int base = blockIdx.x * FPB;
    const float4* v4 = reinterpret_cast<const float4*>(vote + base);
    for (int j = 0; j < 16; ++j) {
        int q = threadIdx.x + j * 256;
        if (q >= FPB / 4) break;
        int e = base + q * 4;
        if (e >= TOTE) break;
        float4 v = v4[q];
        float vals[4] = {v.x, v.y, v.z, v.w};
#pragma unroll
        for (int c2 = 0; c2 < 4; ++c2) {
            if (vals[c2] != 0.0f) {
                int ee = e + c2;
                int row = ee / NR;                 // (h*122+w)*60 + a
                int r   = ee - row * NR;
                int a   = row % NA;
                int pix = row / NA;
                ri[a * NPIX + pix] = (uint8_t)r;
            }
        }
    }
}

// ---------------- Kernel B: per-(b,c) Hough accumulation + argmax -----------
__global__ __launch_bounds__(256) void hough_argmax(const float* __restrict__ pred,
                                                    const uint8_t* __restrict__ ri,
                                                    int* __restrict__ idx_out) {
    __shared__ float s_pred[NPIX];
    __shared__ float s_ht[NA * NR];
    __shared__ float s_rv[256];
    __shared__ int   s_ri[256];

    const int bc  = blockIdx.x;
    const int tid = threadIdx.x;
    // replicate jnp: floor(float32(i) * float32(in/out))
    const float C1 = (float)(288.0 / 26.0);
    const float C2 = (float)(800.0 / 122.0);

    for (int p = tid; p < NPIX; p += 256) {
        int h = p / W_HT;
        int w = p - h * W_HT;
        int hi = (int)floorf((float)h * C1);
        int wi = (int)floorf((float)w * C2);
        s_pred[p] = pred[(bc * PH + hi) * PW + wi];
    }
    for (int i = tid; i < NA * NR; i += 256) s_ht[i] = 0.0f;
    __syncthreads();

    const int wv = tid >> 6;      // wave 0..3 owns 15 disjoint angles
    const int lane = tid & 63;
    for (int j = 0; j < 15; ++j) {
        int a = wv * 15 + j;
        const uint8_t* ria = ri + a * NPIX;
        float* row = s_ht + a * NR;
        for (int p = lane; p < NPIX; p += 64) {
            atomicAdd(&row[ria[p]], s_pred[p]);
        }
    }
    __syncthreads();

    // first-occurrence argmax (numpy semantics: strict >, ties -> smaller idx)
    float bv = -1.0f; int bi = 0;
    for (int i = tid; i < NA * NR; i += 256) {
        float v = s_ht[i];
        if (v > bv) { bv = v; bi = i; }
    }
    s_rv[tid] = bv; s_ri[tid] = bi;
    __syncthreads();
    for (int s = 128; s > 0; s >>= 1) {
        if (tid < s) {
            float ov = s_rv[tid + s]; int oi = s_ri[tid + s];
            if (ov > s_rv[tid] || (ov == s_rv[tid] && oi < s_ri[tid])) {
                s_rv[tid] = ov; s_ri[tid] = oi;
            }
        }
        __syncthreads();
    }
    if (tid == 0) idx_out[bc] = s_ri[0];
}

// ---------------- Kernel C: gather + L1-normalize + loss --------------------
__global__ __launch_bounds__(64) void loss_kernel(const float* __restrict__ ht,
                                                  const float* __restrict__ pexist,
                                                  const int* __restrict__ idx_in,
                                                  float* __restrict__ out) {
    const int b = blockIdx.x;
    const int l = threadIdx.x;
    const int p = l >> 2;     // pair 0..15
    const int s = l & 3;      // sub-lane within pair
    const int c = p >> 2;     // channel for ht
    const int k = p & 3;      // channel for idx/exist

    int fidx = idx_in[b * 4 + k];
    int a0 = fidx / NR;
    int r  = fidx - a0 * NR;
    const float* htc = ht + (size_t)((b * 4 + c) * NA) * NR;

    float acc = 0.0f;
    for (int a = s; a < NA; a += 4) acc += fabsf(htc[a * NR + r]);
    acc += __shfl_xor(acc, 1);
    acc += __shfl_xor(acc, 2);

    float term = 0.0f;
    if (s == 0) {
        float l1 = fmaxf(acc, 1e-12f);
        float g  = htc[a0 * NR + r] / l1;
        float ex = (pexist[b * 4 + k] > 0.9f) ? 1.0f : 0.0f;
        term = -logf(g + 1e-12f) * ex;
    }
    for (int off = 32; off > 0; off >>= 1) term += __shfl_down(term, off);
    if (l == 0) out[b] = term * (1.0f / 16.0f);
}

extern "C" void kernel_launch(void* const* d_in, const int* in_sizes, int n_in,
                              void* d_out, int out_size, void* d_ws, size_t ws_size,
                              hipStream_t stream) {
    const float* ht     = (const float*)d_in[0];
    const float* pred   = (const float*)d_in[1];
    const float* pexist = (const float*)d_in[2];
    const float* vote   = (const float*)d_in[3];

    uint8_t* ri  = (uint8_t*)d_ws;
    int*     idx = (int*)((char*)d_ws + 190336);   // NROW rounded up to 64

    build_ri<<<(TOTE + 15999) / 16000, 256, 0, stream>>>(vote, ri);
    hough_argmax<<<NB * NC, 256, 0, stream>>>(pred, ri, idx);
    loss_kernel<<<NB, 64, 0, stream>>>(ht, pexist, idx, (float*)d_out);
}

// Round 2
// 106.964 us; speedup vs baseline: 3.0167x; 3.0167x over previous
//
#include <hip/hip_runtime.h>
#include <hip/hip_bf16.h>
#include <stdint.h>

#define H_HT 26
#define W_HT 122
#define NPIX (H_HT * W_HT)   // 3172
#define NA 60
#define NR 125
#define NROW (NPIX * NA)     // 190320
#define TOTE (NROW * NR)     // 23790000
#define NB 32
#define NC 4
#define NBC (NB * NC)        // 128
#define PH 288
#define PW 800
#define AG 5                 // angles per hough block
#define NG (NA / AG)         // 12 angle-groups

// ---- workspace layout (bytes) ----
#define WS_RI    0                         // uint8 [60*3172]        190320
#define WS_OFF   190336                    // int32 [60*126]          30240
#define WS_LIST  220608                    // uint16[60*3172]        380640
#define WS_PREDS 601280                    // float [128*3172]      1624064
#define WS_PV    2225344                   // float [1536]             6144
#define WS_PI    2231488                   // int32 [1536]             6144
#define WS_IDX   2237632                   // int32 [128]               512

// ---------------- Kernel A: extract one-hot rho index from vote_index -------
__global__ __launch_bounds__(256) void build_ri(const float* __restrict__ vote,
                                                uint8_t* __restrict__ ri) {
    const int FPB = 16000;                 // floats per block (64 KB)
    int base = blockIdx.x * FPB;
    const float4* v4 = reinterpret_cast<const float4*>(vote + base);
    for (int j = 0; j < 16; ++j) {
        int q = threadIdx.x + j * 256;
        if (q >= FPB / 4) break;
        int e = base + q * 4;
        if (e >= TOTE) break;
        float4 v = v4[q];
        float vals[4] = {v.x, v.y, v.z, v.w};
#pragma unroll
        for (int c2 = 0; c2 < 4; ++c2) {
            if (vals[c2] != 0.0f) {
                int ee = e + c2;
                int row = ee / NR;                 // (h*122+w)*60 + a
                int r   = ee - row * NR;
                int a   = row % NA;
                int pix = row / NA;
                ri[a * NPIX + pix] = (uint8_t)r;
            }
        }
    }
}

// ---------------- Kernel B: invert ri into CSR bucket lists per angle -------
__global__ __launch_bounds__(256) void build_csr(const uint8_t* __restrict__ ri,
                                                 int* __restrict__ off,
                                                 uint16_t* __restrict__ list) {
    __shared__ int s_cnt[NR];
    __shared__ int s_pre[NR + 1];
    __shared__ int s_cur[NR];
    const int a = blockIdx.x;
    const int tid = threadIdx.x;
    for (int i = tid; i < NR; i += 256) s_cnt[i] = 0;
    __syncthreads();
    for (int p = tid; p < NPIX; p += 256)
        atomicAdd(&s_cnt[ri[a * NPIX + p]], 1);
    __syncthreads();
    if (tid == 0) {
        int s = 0;
        for (int r = 0; r < NR; ++r) { s_pre[r] = s; s += s_cnt[r]; }
        s_pre[NR] = s;
    }
    __syncthreads();
    for (int r = tid; r < NR + 1; r += 256) off[a * (NR + 1) + r] = s_pre[r];
    for (int r = tid; r < NR; r += 256) s_cur[r] = s_pre[r];
    __syncthreads();
    for (int p = tid; p < NPIX; p += 256) {
        int r = ri[a * NPIX + p];
        int slot = atomicAdd(&s_cur[r], 1);
        list[a * NPIX + slot] = (uint16_t)p;
    }
}

// ---------------- Kernel C: materialize nearest-resized pred ----------------
__global__ __launch_bounds__(256) void gather_pred(const float* __restrict__ pred,
                                                   float* __restrict__ pred_s) {
    const int bc = blockIdx.x;
    const int tid = threadIdx.x;
    const float C1 = (float)(288.0 / 26.0);
    const float C2 = (float)(800.0 / 122.0);
    for (int p = tid; p < NPIX; p += 256) {
        int h = p / W_HT;
        int w = p - h * W_HT;
        int hi = (int)floorf((float)h * C1);
        int wi = (int)floorf((float)w * C2);
        pred_s[bc * NPIX + p] = pred[(bc * PH + hi) * PW + wi];
    }
}

// ---------------- Kernel D: per-(bc, angle-group) bin sums + partial argmax -
__global__ __launch_bounds__(256) void hough_partial(const float* __restrict__ pred_s,
                                                     const int* __restrict__ off,
                                                     const uint16_t* __restrict__ list,
                                                     float* __restrict__ pv,
                                                     int* __restrict__ pi) {
    __shared__ float    s_pred[NPIX];
    __shared__ uint16_t s_list[AG * NPIX];
    __shared__ float    s_rv[256];
    __shared__ int      s_ri2[256];

    const int blk = blockIdx.x;
    const int bc  = blk / NG;
    const int g   = blk - bc * NG;
    const int a0  = g * AG;
    const int tid = threadIdx.x;

    // stage pred_s (coalesced)
    const float* ps = pred_s + bc * NPIX;
    for (int p = tid; p < NPIX; p += 256) s_pred[p] = ps[p];
    // stage 5 angles' pixel lists (contiguous, load as uint32)
    {
        const uint32_t* src = reinterpret_cast<const uint32_t*>(list + a0 * NPIX);
        uint32_t* dst = reinterpret_cast<uint32_t*>(s_list);
        const int n32 = AG * NPIX / 2;   // 7930
        for (int i = tid; i < n32; i += 256) dst[i] = src[i];
    }
    __syncthreads();

    float bv = -1.0f; int bi = 0;
    for (int lb = tid; lb < AG * NR; lb += 256) {
        int la = lb / NR;
        int r  = lb - la * NR;
        int a  = a0 + la;
        int o0 = off[a * (NR + 1) + r];
        int o1 = off[a * (NR + 1) + r + 1];
        const uint16_t* lp = s_list + la * NPIX;
        float s = 0.0f;
        for (int j = o0; j < o1; ++j) s += s_pred[lp[j]];
        int gbin = a * NR + r;
        if (s > bv) { bv = s; bi = gbin; }
    }
    s_rv[tid] = bv; s_ri2[tid] = bi;
    __syncthreads();
    for (int s = 128; s > 0; s >>= 1) {
        if (tid < s) {
            float ov = s_rv[tid + s]; int oi = s_ri2[tid + s];
            if (ov > s_rv[tid] || (ov == s_rv[tid] && oi < s_ri2[tid])) {
                s_rv[tid] = ov; s_ri2[tid] = oi;
            }
        }
        __syncthreads();
    }
    if (tid == 0) { pv[blk] = s_rv[0]; pi[blk] = s_ri2[0]; }
}

// ---------------- Kernel E: reduce angle-group partials ---------------------
__global__ __launch_bounds__(128) void final_argmax(const float* __restrict__ pv,
                                                    const int* __restrict__ pi,
                                                    int* __restrict__ idx) {
    int bc = threadIdx.x;
    if (bc >= NBC) return;
    float bv = -1.0f; int bi = 0x7fffffff;
    for (int g = 0; g < NG; ++g) {
        float v = pv[bc * NG + g];
        int   i = pi[bc * NG + g];
        if (v > bv || (v == bv && i < bi)) { bv = v; bi = i; }
    }
    idx[bc] = bi;
}

// ---------------- Kernel F: gather + L1-normalize + loss --------------------
__global__ __launch_bounds__(64) void loss_kernel(const float* __restrict__ ht,
                                                  const float* __restrict__ pexist,
                                                  const int* __restrict__ idx_in,
                                                  float* __restrict__ out) {
    const int b = blockIdx.x;
    const int l = threadIdx.x;
    const int p = l >> 2;     // pair 0..15
    const int s = l & 3;      // sub-lane within pair
    const int c = p >> 2;     // channel for ht
    const int k = p & 3;      // channel for idx/exist

    int fidx = idx_in[b * 4 + k];
    int a0 = fidx / NR;
    int r  = fidx - a0 * NR;
    const float* htc = ht + (size_t)((b * 4 + c) * NA) * NR;

    float acc = 0.0f;
    for (int a = s; a < NA; a += 4) acc += fabsf(htc[a * NR + r]);
    acc += __shfl_xor(acc, 1);
    acc += __shfl_xor(acc, 2);

    float term = 0.0f;
    if (s == 0) {
        float l1 = fmaxf(acc, 1e-12f);
        float g  = htc[a0 * NR + r] / l1;
        float ex = (pexist[b * 4 + k] > 0.9f) ? 1.0f : 0.0f;
        term = -logf(g + 1e-12f) * ex;
    }
    for (int offt = 32; offt > 0; offt >>= 1) term += __shfl_down(term, offt);
    if (l == 0) out[b] = term * (1.0f / 16.0f);
}

extern "C" void kernel_launch(void* const* d_in, const int* in_sizes, int n_in,
                              void* d_out, int out_size, void* d_ws, size_t ws_size,
                              hipStream_t stream) {
    const float* ht     = (const float*)d_in[0];
    const float* pred   = (const float*)d_in[1];
    const float* pexist = (const float*)d_in[2];
    const float* vote   = (const float*)d_in[3];

    char* ws = (char*)d_ws;
    uint8_t*  ri     = (uint8_t*) (ws + WS_RI);
    int*      off    = (int*)     (ws + WS_OFF);
    uint16_t* list   = (uint16_t*)(ws + WS_LIST);
    float*    pred_s = (float*)   (ws + WS_PREDS);
    float*    pv     = (float*)   (ws + WS_PV);
    int*      pi     = (int*)     (ws + WS_PI);
    int*      idx    = (int*)     (ws + WS_IDX);

    build_ri<<<(TOTE + 15999) / 16000, 256, 0, stream>>>(vote, ri);
    build_csr<<<NA, 256, 0, stream>>>(ri, off, list);
    gather_pred<<<NBC, 256, 0, stream>>>(pred, pred_s);
    hough_partial<<<NBC * NG, 256, 0, stream>>>(pred_s, off, list, pv, pi);
    final_argmax<<<1, 128, 0, stream>>>(pv, pi, idx);
    loss_kernel<<<NB, 64, 0, stream>>>(ht, pexist, idx, (float*)d_out);
}

// Round 3
// 81.676 us; speedup vs baseline: 3.9508x; 1.3096x over previous
//
#include <hip/hip_runtime.h>
#include <hip/hip_bf16.h>
#include <stdint.h>

#define H_HT 26
#define W_HT 122
#define NPIX (H_HT * W_HT)   // 3172
#define NA 60
#define NR 125
#define NROW (NPIX * NA)     // 190320
#define TOTE (NROW * NR)     // 23790000
#define NB 32
#define NC 4
#define NBC (NB * NC)        // 128
#define PH 288
#define PW 800
#define AG 4                 // angles per hough block
#define NG (NA / AG)         // 15 angle-groups

// ---- workspace layout (bytes) ----
#define WS_RI    0                         // uint8 [60*3172]        190320
#define WS_OFF   190336                    // int32 [60*126]          30240
#define WS_LIST  220608                    // uint16[60*3172]        380640
#define WS_PREDS 601280                    // float [128*3172]      1624064
#define WS_PV    2225344                   // float [128*15]           7680
#define WS_PI    2233024                   // int32 [128*15]           7680

// ---------------- Kernel A: extract one-hot rho index from vote_index -------
__global__ __launch_bounds__(256) void build_ri(const float* __restrict__ vote,
                                                uint8_t* __restrict__ ri) {
    const int FPB = 16000;                 // floats per block (64 KB)
    int base = blockIdx.x * FPB;
    const float4* v4 = reinterpret_cast<const float4*>(vote + base);
    for (int j = 0; j < 16; ++j) {
        int q = threadIdx.x + j * 256;
        if (q >= FPB / 4) break;
        int e = base + q * 4;
        if (e >= TOTE) break;
        float4 v = v4[q];
        float vals[4] = {v.x, v.y, v.z, v.w};
#pragma unroll
        for (int c2 = 0; c2 < 4; ++c2) {
            if (vals[c2] != 0.0f) {
                int ee = e + c2;
                int row = ee / NR;                 // (h*122+w)*60 + a
                int r   = ee - row * NR;
                int a   = row % NA;
                int pix = row / NA;
                ri[a * NPIX + pix] = (uint8_t)r;
            }
        }
    }
}

// ---------------- Kernel B: invert ri into CSR bucket lists per angle -------
__global__ __launch_bounds__(256) void build_csr(const uint8_t* __restrict__ ri,
                                                 int* __restrict__ off,
                                                 uint16_t* __restrict__ list) {
    __shared__ int s_cnt[NR];
    __shared__ int s_pre[NR + 1];
    __shared__ int s_cur[NR];
    const int a = blockIdx.x;
    const int tid = threadIdx.x;
    for (int i = tid; i < NR; i += 256) s_cnt[i] = 0;
    __syncthreads();
    for (int p = tid; p < NPIX; p += 256)
        atomicAdd(&s_cnt[ri[a * NPIX + p]], 1);
    __syncthreads();
    if (tid == 0) {
        int s = 0;
        for (int r = 0; r < NR; ++r) { s_pre[r] = s; s += s_cnt[r]; }
        s_pre[NR] = s;
    }
    __syncthreads();
    for (int r = tid; r < NR + 1; r += 256) off[a * (NR + 1) + r] = s_pre[r];
    for (int r = tid; r < NR; r += 256) s_cur[r] = s_pre[r];
    __syncthreads();
    for (int p = tid; p < NPIX; p += 256) {
        int r = ri[a * NPIX + p];
        int slot = atomicAdd(&s_cur[r], 1);
        list[a * NPIX + slot] = (uint16_t)p;
    }
}

// ---------------- Kernel C: materialize nearest-resized pred ----------------
__global__ __launch_bounds__(256) void gather_pred(const float* __restrict__ pred,
                                                   float* __restrict__ pred_s) {
    const int bc = blockIdx.x;
    const int tid = threadIdx.x;
    const float C1 = (float)(288.0 / 26.0);
    const float C2 = (float)(800.0 / 122.0);
    for (int p = tid; p < NPIX; p += 256) {
        int h = p / W_HT;
        int w = p - h * W_HT;
        int hi = (int)floorf((float)h * C1);
        int wi = (int)floorf((float)w * C2);
        pred_s[bc * NPIX + p] = pred[(bc * PH + hi) * PW + wi];
    }
}

// ---------------- Kernel D: per-(bc, angle-group) bin sums + partial argmax -
// Phase 1: uniform gather into list order (independent loads, no imbalance).
// Phase 2: per-bin contiguous LDS run sum (independent addresses, 2 accums).
__global__ __launch_bounds__(256) void hough_partial(const float* __restrict__ pred_s,
                                                     const int* __restrict__ off,
                                                     const uint16_t* __restrict__ list,
                                                     float* __restrict__ pv,
                                                     int* __restrict__ pi) {
    __shared__ float s_gath[AG * NPIX];    // 50752 B
    __shared__ float s_rv[256];
    __shared__ int   s_ri2[256];

    const int blk = blockIdx.x;
    const int bc  = blk / NG;
    const int g   = blk - bc * NG;
    const int a0  = g * AG;
    const int tid = threadIdx.x;

    const float* ps = pred_s + bc * NPIX;
    const uint32_t* lp32 = reinterpret_cast<const uint32_t*>(list + a0 * NPIX);
    for (int j2 = tid; j2 < AG * NPIX / 2; j2 += 256) {
        uint32_t w2 = lp32[j2];
        int j = j2 * 2;
        s_gath[j]     = ps[w2 & 0xffffu];
        s_gath[j + 1] = ps[w2 >> 16];
    }
    __syncthreads();

    float bv = -1.0f; int bi = 0;
    for (int lb = tid; lb < AG * NR; lb += 256) {
        int la = lb / NR;
        int r  = lb - la * NR;
        int a  = a0 + la;
        int o0 = off[a * (NR + 1) + r];
        int o1 = off[a * (NR + 1) + r + 1];
        const float* gp = s_gath + la * NPIX;
        float s0 = 0.0f, s1 = 0.0f;
        int j = o0;
        for (; j + 1 < o1; j += 2) { s0 += gp[j]; s1 += gp[j + 1]; }
        if (j < o1) s0 += gp[j];
        float s = s0 + s1;
        int gbin = a * NR + r;
        if (s > bv) { bv = s; bi = gbin; }
    }
    s_rv[tid] = bv; s_ri2[tid] = bi;
    __syncthreads();
    for (int s = 128; s > 0; s >>= 1) {
        if (tid < s) {
            float ov = s_rv[tid + s]; int oi = s_ri2[tid + s];
            if (ov > s_rv[tid] || (ov == s_rv[tid] && oi < s_ri2[tid])) {
                s_rv[tid] = ov; s_ri2[tid] = oi;
            }
        }
        __syncthreads();
    }
    if (tid == 0) { pv[blk] = s_rv[0]; pi[blk] = s_ri2[0]; }
}

// ---------------- Kernel E: final argmax + gather + L1-normalize + loss -----
__global__ __launch_bounds__(64) void loss_kernel(const float* __restrict__ ht,
                                                  const float* __restrict__ pexist,
                                                  const float* __restrict__ pv,
                                                  const int* __restrict__ pi,
                                                  float* __restrict__ out) {
    const int b = blockIdx.x;
    const int l = threadIdx.x;
    const int p = l >> 2;     // pair 0..15
    const int s = l & 3;      // sub-lane within pair
    const int c = p >> 2;     // channel for ht
    const int k = p & 3;      // channel for idx/exist

    // argmax over the NG group partials for (b, k); all lanes of the same k
    // read the same addresses -> broadcast transactions.
    const int bck = b * 4 + k;
    float bv = -1.0f; int fidx = 0x7fffffff;
    for (int g2 = 0; g2 < NG; ++g2) {
        float v = pv[bck * NG + g2];
        int   i = pi[bck * NG + g2];
        if (v > bv || (v == bv && i < fidx)) { bv = v; fidx = i; }
    }

    int a0 = fidx / NR;
    int r  = fidx - a0 * NR;
    const float* htc = ht + (size_t)((b * 4 + c) * NA) * NR;

    float acc = 0.0f;
    for (int a = s; a < NA; a += 4) acc += fabsf(htc[a * NR + r]);
    acc += __shfl_xor(acc, 1);
    acc += __shfl_xor(acc, 2);

    float term = 0.0f;
    if (s == 0) {
        float l1 = fmaxf(acc, 1e-12f);
        float gg = htc[a0 * NR + r] / l1;
        float ex = (pexist[b * 4 + k] > 0.9f) ? 1.0f : 0.0f;
        term = -logf(gg + 1e-12f) * ex;
    }
    for (int offt = 32; offt > 0; offt >>= 1) term += __shfl_down(term, offt);
    if (l == 0) out[b] = term * (1.0f / 16.0f);
}

extern "C" void kernel_launch(void* const* d_in, const int* in_sizes, int n_in,
                              void* d_out, int out_size, void* d_ws, size_t ws_size,
                              hipStream_t stream) {
    const float* ht     = (const float*)d_in[0];
    const float* pred   = (const float*)d_in[1];
    const float* pexist = (const float*)d_in[2];
    const float* vote   = (const float*)d_in[3];

    char* ws = (char*)d_ws;
    uint8_t*  ri     = (uint8_t*) (ws + WS_RI);
    int*      off    = (int*)     (ws + WS_OFF);
    uint16_t* list   = (uint16_t*)(ws + WS_LIST);
    float*    pred_s = (float*)   (ws + WS_PREDS);
    float*    pv     = (float*)   (ws + WS_PV);
    int*      pi     = (int*)     (ws + WS_PI);

    build_ri<<<(TOTE + 15999) / 16000, 256, 0, stream>>>(vote, ri);
    build_csr<<<NA, 256, 0, stream>>>(ri, off, list);
    gather_pred<<<NBC, 256, 0, stream>>>(pred, pred_s);
    hough_partial<<<NBC * NG, 256, 0, stream>>>(pred_s, off, list, pv, pi);
    loss_kernel<<<NB, 64, 0, stream>>>(ht, pexist, pv, pi, (float*)d_out);
}